// Round 5
// baseline (417.353 us; speedup 1.0000x reference)
//
#include <hip/hip_runtime.h>
#include <hip/hip_cooperative_groups.h>
#include <hip/hip_bf16.h>
#include <math.h>

namespace cg = cooperative_groups;

#define B_SZ 16
#define T_SZ 128
#define N_P 12
#define D_SZ 1024
#define D2_SZ 2048
#define BT 2048          // B*T tokens
#define KDIM 2048        // inner dim of projections (2D)
#define EALL 8192        // 4*1024 (tb,pb,ta,pa) + 2*2048 (gb,ga)
#define EPROJ 4096       // tb|pb|ta|pa row width

typedef __attribute__((ext_vector_type(8))) short short8;    // 8 bf16 = 4 VGPRs
typedef __attribute__((ext_vector_type(4))) float floatx4;   // MFMA C/D

__device__ inline void gload_lds16(const void* g, void* l) {
  __builtin_amdgcn_global_load_lds(
      (const __attribute__((address_space(1))) void*)g,
      (__attribute__((address_space(3))) void*)l, 16, 0, 0);
}

__device__ inline unsigned short f2bf(float x) {
  union { __hip_bfloat16 h; unsigned short u; } cv;
  cv.h = __float2bfloat16(x);
  return cv.u;
}
__device__ inline float bf2f(unsigned short u) {
  return __uint_as_float(((unsigned)u) << 16);
}

// ---------------------------------------------------------------------------
// Mega kernel: 256 blocks x 512 threads, cooperative.
//   P1: build_n (8 tokens/block, 2 in flight across block halves) + weight cvt
//   P2: projection GEMM (round-1 verified ring-of-4 schedule, 256x256 tile)
//   P3: score (32 blocks, 128x128 tile, K=1024, ring-of-4 pipeline)
//   P4: PV (256 blocks, register-only)
// LDS: 128 KiB union (P1 wred / P2 ring 4x32KB / P3 ring 4x16KB).
// ---------------------------------------------------------------------------
__global__ __launch_bounds__(512, 2) void biute_mega(
    const float* __restrict__ feat, const float* __restrict__ Wq,
    const float* __restrict__ Wtb, const float* __restrict__ Wpb,
    const float* __restrict__ Wta, const float* __restrict__ Wpa,
    const float* __restrict__ Wgb, const float* __restrict__ Wga,
    unsigned short* __restrict__ Nbf, unsigned short* __restrict__ Wb,
    unsigned short* __restrict__ Cproj, unsigned short* __restrict__ Gbt,
    unsigned short* __restrict__ Gat, unsigned short* __restrict__ Sbf,
    float* __restrict__ out) {
  __shared__ __align__(16) unsigned short lds[4 * 16384];  // 128 KiB
  cg::grid_group grid = cg::this_grid();
  const int bid = blockIdx.x;
  const int tid = threadIdx.x;
  const int lane = tid & 63;
  const int w = tid >> 6;           // 0..7
  const int quad = lane >> 4;
  const int l15 = lane & 15;

  // ===================== P1: prep =====================
  {
    const int half = tid >> 8;          // 0/1: two tokens in flight
    const int ht = tid & 255;
    const int wavh = (tid >> 6) & 3;    // wave within half
    float* wred = (float*)lds;          // [2][N_P][4]
    const float4* wq4 = (const float4*)Wq;

    float4 q = {0.f, 0.f, 0.f, 0.f};
#pragma unroll
    for (int m = 0; m < N_P; ++m) {
      const float4 v = wq4[m * 256 + ht];
      q.x += v.x; q.y += v.y; q.z += v.z; q.w += v.w;
    }
    for (int it = 0; it < 4; ++it) {
      const int t = bid * 8 + it * 2 + half;
      const float4* fb4 = (const float4*)(feat + (size_t)t * N_P * D_SZ);
      float4 fv[N_P];
      float part[N_P];
#pragma unroll
      for (int n = 0; n < N_P; ++n) {
        const float4 f = fb4[n * 256 + ht];
        fv[n] = f;
        part[n] = f.x * q.x + f.y * q.y + f.z * q.z + f.w * q.w;
      }
#pragma unroll
      for (int n = 0; n < N_P; ++n) {
        float v = part[n];
#pragma unroll
        for (int off = 32; off; off >>= 1) v += __shfl_down(v, off);
        if (lane == 0) wred[(half * N_P + n) * 4 + wavh] = v;
      }
      __syncthreads();
      float wv[N_P];
#pragma unroll
      for (int n = 0; n < N_P; ++n) {
        const float* p = &wred[(half * N_P + n) * 4];
        wv[n] = p[0] + p[1] + p[2] + p[3];
      }
      float4 g = {0.f, 0.f, 0.f, 0.f};
      float4 fm = {-INFINITY, -INFINITY, -INFINITY, -INFINITY};
#pragma unroll
      for (int n = 0; n < N_P; ++n) {
        const float4 f = fv[n];
        g.x += wv[n] * f.x; g.y += wv[n] * f.y;
        g.z += wv[n] * f.z; g.w += wv[n] * f.w;
        fm.x = fmaxf(fm.x, f.x); fm.y = fmaxf(fm.y, f.y);
        fm.z = fmaxf(fm.z, f.z); fm.w = fmaxf(fm.w, f.w);
      }
      ushort4 og, of;
      og.x = f2bf(g.x); og.y = f2bf(g.y); og.z = f2bf(g.z); og.w = f2bf(g.w);
      of.x = f2bf(fm.x); of.y = f2bf(fm.y); of.z = f2bf(fm.z); of.w = f2bf(fm.w);
      *(ushort4*)&Nbf[(size_t)t * D2_SZ + ht * 4] = og;
      *(ushort4*)&Nbf[(size_t)t * D2_SZ + D_SZ + ht * 4] = of;
      __syncthreads();   // wred reused next iteration
    }
    // weight conversion: 4,194,304 float4 over 131072 threads -> 32 each
    const int gtid = bid * 512 + tid;
    for (int itc = 0; itc < 32; ++itc) {
      const int idx = gtid + itc * 131072;
      const int r = idx >> 19;          // 512K-float4 chunk
      const int i = idx & 524287;
      const float4* sb;
      size_t db;
      switch (r) {
        case 0: sb = (const float4*)Wtb;           db = 0u * 524288u; break;
        case 1: sb = (const float4*)Wpb;           db = 1u * 524288u; break;
        case 2: sb = (const float4*)Wta;           db = 2u * 524288u; break;
        case 3: sb = (const float4*)Wpa;           db = 3u * 524288u; break;
        case 4: sb = (const float4*)Wgb;           db = 2097152u; break;
        case 5: sb = (const float4*)Wgb + 524288;  db = 2097152u + 524288u; break;
        case 6: sb = (const float4*)Wga;           db = 3145728u; break;
        default: sb = (const float4*)Wga + 524288; db = 3145728u + 524288u; break;
      }
      const float4 v = sb[i];
      ushort4 o;
      o.x = f2bf(v.x); o.y = f2bf(v.y); o.z = f2bf(v.z); o.w = f2bf(v.w);
      ((ushort4*)Wb)[db + i] = o;
    }
  }
  grid.sync();

  // ===================== P2: projection GEMM =====================
  {
    const int wm = (w >> 2) * 128;    // wave row (2 waves in M)
    const int wn = (w & 3) * 64;      // wave col (4 waves in N)
    const int swz = (bid & 7) * 32 + (bid >> 3);   // XCD-bijective
    const int m0 = (swz & 7) * 256;
    const int be = swz >> 3;          // 0..31 E-tile
    const int e0 = be * 256;

    floatx4 acc[8][4];
#pragma unroll
    for (int mt = 0; mt < 8; ++mt)
#pragma unroll
      for (int nt = 0; nt < 4; ++nt) {
        floatx4 z = {0.f, 0.f, 0.f, 0.f};
        acc[mt][nt] = z;
      }

    const unsigned short* srcA[2];
    const unsigned short* srcB[2];
    int dstOff[2];
#pragma unroll
    for (int c = 0; c < 2; ++c) {
      const int s = tid + c * 512;
      const int row = s >> 2;
      const int ccg = (s & 3) ^ ((row >> 1) & 3);
      srcA[c] = Nbf + (size_t)(m0 + row) * KDIM + ccg * 8;
      srcB[c] = Wb + (size_t)(e0 + row) * KDIM + ccg * 8;
      dstOff[c] = s * 8;
    }

    int aofs[8], bofs[4];
#pragma unroll
    for (int mt = 0; mt < 8; ++mt) {
      const int row = wm + mt * 16 + l15;
      aofs[mt] = row * 32 + ((quad ^ ((row >> 1) & 3)) * 8);
    }
#pragma unroll
    for (int nt = 0; nt < 4; ++nt) {
      const int row = wn + nt * 16 + l15;
      bofs[nt] = 8192 + row * 32 + ((quad ^ ((row >> 1) & 3)) * 8);
    }

    auto STAGE = [&](int t) {
      const int rb_ = (t & 3) * 16384;
      const int k0_ = t * 32;
#pragma unroll
      for (int c = 0; c < 2; ++c) {
        gload_lds16(srcA[c] + k0_, &lds[rb_ + dstOff[c]]);
        gload_lds16(srcB[c] + k0_, &lds[rb_ + 8192 + dstOff[c]]);
      }
    };

    STAGE(0); STAGE(1); STAGE(2);
    __builtin_amdgcn_sched_barrier(0);
    asm volatile("s_waitcnt vmcnt(8)" ::: "memory");
    __builtin_amdgcn_sched_barrier(0);
    __builtin_amdgcn_s_barrier();
    __builtin_amdgcn_sched_barrier(0);

    for (int t = 0; t < 64; ++t) {
      const int rb = (t & 3) * 16384;
      short8 a[8], b[4];
#pragma unroll
      for (int mt = 0; mt < 8; ++mt) a[mt] = *(const short8*)&lds[rb + aofs[mt]];
#pragma unroll
      for (int nt = 0; nt < 4; ++nt) b[nt] = *(const short8*)&lds[rb + bofs[nt]];
      if (t + 3 < 64) STAGE(t + 3);
      __builtin_amdgcn_s_setprio(1);
#pragma unroll
      for (int mt = 0; mt < 8; ++mt)
#pragma unroll
        for (int nt = 0; nt < 4; ++nt)
          acc[mt][nt] = __builtin_amdgcn_mfma_f32_16x16x32_bf16(
              a[mt], b[nt], acc[mt][nt], 0, 0, 0);
      __builtin_amdgcn_s_setprio(0);
      __builtin_amdgcn_sched_barrier(0);
      if (t + 3 < 64) {
        asm volatile("s_waitcnt vmcnt(8)" ::: "memory");
      } else if (t + 2 < 64) {
        asm volatile("s_waitcnt vmcnt(4)" ::: "memory");
      } else if (t + 1 < 64) {
        asm volatile("s_waitcnt vmcnt(0)" ::: "memory");
      }
      __builtin_amdgcn_sched_barrier(0);
      __builtin_amdgcn_s_barrier();
      __builtin_amdgcn_sched_barrier(0);
    }

    if (be < 16) {
#pragma unroll
      for (int mt = 0; mt < 8; ++mt)
#pragma unroll
        for (int nt = 0; nt < 4; ++nt) {
          const int col = e0 + wn + nt * 16 + l15;
#pragma unroll
          for (int r = 0; r < 4; ++r) {
            const int rowg = m0 + wm + mt * 16 + quad * 4 + r;
            Cproj[(size_t)rowg * EPROJ + col] = f2bf(acc[mt][nt][r]);
          }
        }
    } else {
      unsigned short* Gt = (be < 24) ? Gbt : Gat;
      const int fb = e0 - ((be < 24) ? 4096 : 6144);
#pragma unroll
      for (int mt = 0; mt < 8; ++mt)
#pragma unroll
        for (int nt = 0; nt < 4; ++nt) {
          const int f = fb + wn + nt * 16 + l15;
          const int tok0 = m0 + wm + mt * 16 + quad * 4;
          ushort4 o;
          o.x = f2bf(acc[mt][nt][0]); o.y = f2bf(acc[mt][nt][1]);
          o.z = f2bf(acc[mt][nt][2]); o.w = f2bf(acc[mt][nt][3]);
          *(ushort4*)&Gt[(size_t)f * BT + tok0] = o;
        }
    }
  }
  grid.sync();

  // ===================== P3: score (32 blocks) =====================
  if (bid < 32) {
    const int b = bid & 15;
    const int br = bid >> 4;
    const int aoff = br ? 2048 : 0;
    const int boff = aoff + 1024;
    const int t0 = b * T_SZ;
    const int swm = (w >> 2) * 64;   // i
    const int swn = (w & 3) * 32;    // j

    floatx4 sacc[4][2];
#pragma unroll
    for (int mt = 0; mt < 4; ++mt)
#pragma unroll
      for (int nt = 0; nt < 2; ++nt) {
        floatx4 z = {0.f, 0.f, 0.f, 0.f};
        sacc[mt][nt] = z;
      }

    const int srow = tid >> 2;
    const int sccg = (tid & 3) ^ ((srow >> 1) & 3);
    const unsigned short* gA =
        Cproj + (size_t)(t0 + srow) * EPROJ + aoff + sccg * 8;
    const unsigned short* gB =
        Cproj + (size_t)(t0 + srow) * EPROJ + boff + sccg * 8;

    int saofs[4], sbofs[2];
#pragma unroll
    for (int mt = 0; mt < 4; ++mt) {
      const int row = swm + mt * 16 + l15;
      saofs[mt] = row * 32 + ((quad ^ ((row >> 1) & 3)) * 8);
    }
#pragma unroll
    for (int nt = 0; nt < 2; ++nt) {
      const int row = swn + nt * 16 + l15;
      sbofs[nt] = 4096 + row * 32 + ((quad ^ ((row >> 1) & 3)) * 8);
    }

    auto SSTAGE = [&](int t) {
      unsigned short* sl = &lds[(t & 3) * 8192];
      const int k0_ = t * 32;
      gload_lds16(gA + k0_, &sl[tid * 8]);
      gload_lds16(gB + k0_, &sl[4096 + tid * 8]);
    };

    SSTAGE(0); SSTAGE(1); SSTAGE(2);
    __builtin_amdgcn_sched_barrier(0);
    asm volatile("s_waitcnt vmcnt(4)" ::: "memory");
    __builtin_amdgcn_sched_barrier(0);
    __builtin_amdgcn_s_barrier();
    __builtin_amdgcn_sched_barrier(0);

    for (int t = 0; t < 32; ++t) {
      const unsigned short* sl = &lds[(t & 3) * 8192];
      short8 a[4], bb[2];
#pragma unroll
      for (int mt = 0; mt < 4; ++mt) a[mt] = *(const short8*)&sl[saofs[mt]];
#pragma unroll
      for (int nt = 0; nt < 2; ++nt) bb[nt] = *(const short8*)&sl[sbofs[nt]];
      if (t + 3 < 32) SSTAGE(t + 3);
      __builtin_amdgcn_s_setprio(1);
#pragma unroll
      for (int mt = 0; mt < 4; ++mt)
#pragma unroll
        for (int nt = 0; nt < 2; ++nt)
          sacc[mt][nt] = __builtin_amdgcn_mfma_f32_16x16x32_bf16(
              a[mt], bb[nt], sacc[mt][nt], 0, 0, 0);
      __builtin_amdgcn_s_setprio(0);
      __builtin_amdgcn_sched_barrier(0);
      if (t + 3 < 32) {
        asm volatile("s_waitcnt vmcnt(4)" ::: "memory");
      } else if (t + 2 < 32) {
        asm volatile("s_waitcnt vmcnt(2)" ::: "memory");
      } else if (t + 1 < 32) {
        asm volatile("s_waitcnt vmcnt(0)" ::: "memory");
      }
      __builtin_amdgcn_sched_barrier(0);
      __builtin_amdgcn_s_barrier();
      __builtin_amdgcn_sched_barrier(0);
    }

    const float scale = 0.022097086912079608f;  // 1/sqrt(2*1024)
    unsigned short* Sp = Sbf + ((size_t)(br * B_SZ + b)) * T_SZ * T_SZ;
#pragma unroll
    for (int mt = 0; mt < 4; ++mt)
#pragma unroll
      for (int nt = 0; nt < 2; ++nt) {
        const int j = swn + nt * 16 + l15;
#pragma unroll
        for (int r = 0; r < 4; ++r) {
          const int i = swm + mt * 16 + quad * 4 + r;
          const bool keep = br ? (j > i) : (j < i);
          Sp[(size_t)i * T_SZ + j] = f2bf(keep ? sacc[mt][nt][r] * scale : 0.f);
        }
      }
  }
  grid.sync();

  // ===================== P4: PV =====================
  {
    const int ft = bid >> 4;
    const int b = bid & 15;
    const int f0 = ft * 128;
    const int t0 = b * T_SZ;
    const int pwm = (w >> 2) * 64;   // token
    const int pwn = (w & 3) * 32;    // f

    const unsigned short* Sb = Sbf + ((size_t)b) * T_SZ * T_SZ;
    const unsigned short* Sa = Sbf + ((size_t)(B_SZ + b)) * T_SZ * T_SZ;

    floatx4 pacc[4][2];
#pragma unroll
    for (int mt = 0; mt < 4; ++mt)
#pragma unroll
      for (int nt = 0; nt < 2; ++nt) {
        floatx4 z = {0.f, 0.f, 0.f, 0.f};
        pacc[mt][nt] = z;
      }

#pragma unroll
    for (int k0 = 0; k0 < T_SZ; k0 += 32) {
      short8 ab[4], aa[4], bb[2], ba[2];
#pragma unroll
      for (int mt = 0; mt < 4; ++mt) {
        const int i = pwm + mt * 16 + l15;
        ab[mt] = *(const short8*)&Sb[(size_t)i * T_SZ + k0 + quad * 8];
        aa[mt] = *(const short8*)&Sa[(size_t)i * T_SZ + k0 + quad * 8];
      }
#pragma unroll
      for (int nt = 0; nt < 2; ++nt) {
        const int f = f0 + pwn + nt * 16 + l15;
        bb[nt] = *(const short8*)&Gbt[(size_t)f * BT + t0 + k0 + quad * 8];
        ba[nt] = *(const short8*)&Gat[(size_t)f * BT + t0 + k0 + quad * 8];
      }
#pragma unroll
      for (int mt = 0; mt < 4; ++mt)
#pragma unroll
        for (int nt = 0; nt < 2; ++nt) {
          pacc[mt][nt] = __builtin_amdgcn_mfma_f32_16x16x32_bf16(
              ab[mt], bb[nt], pacc[mt][nt], 0, 0, 0);
          pacc[mt][nt] = __builtin_amdgcn_mfma_f32_16x16x32_bf16(
              aa[mt], ba[nt], pacc[mt][nt], 0, 0, 0);
        }
    }

#pragma unroll
    for (int mt = 0; mt < 4; ++mt)
#pragma unroll
      for (int nt = 0; nt < 2; ++nt) {
        const int f = f0 + pwn + nt * 16 + l15;
#pragma unroll
        for (int r = 0; r < 4; ++r) {
          const int tok = t0 + pwm + mt * 16 + quad * 4 + r;
          out[(size_t)tok * D2_SZ + f] =
              pacc[mt][nt][r] + bf2f(Nbf[(size_t)tok * D2_SZ + f]);
        }
      }
  }
}

// ---------------------------------------------------------------------------
extern "C" void kernel_launch(void* const* d_in, const int* in_sizes, int n_in,
                              void* d_out, int out_size, void* d_ws, size_t ws_size,
                              hipStream_t stream) {
  const float* feat = (const float*)d_in[0];
  const float* Wq  = (const float*)d_in[1];
  const float* Wtb = (const float*)d_in[2];
  const float* Wpb = (const float*)d_in[3];
  const float* Wgb = (const float*)d_in[4];  // dict order: gb before ta
  const float* Wta = (const float*)d_in[5];
  const float* Wpa = (const float*)d_in[6];
  const float* Wga = (const float*)d_in[7];
  float* out = (float*)d_out;

  unsigned short* ws = (unsigned short*)d_ws;
  unsigned short* Nbf   = ws;                                 // [2048][2048] bf16
  unsigned short* Wb    = Nbf + (size_t)BT * D2_SZ;           // [8192][2048] bf16
  unsigned short* Cproj = Wb + (size_t)EALL * KDIM;           // [2048][4096] bf16
  unsigned short* Gbt   = Cproj + (size_t)BT * EPROJ;         // [2048][2048] bf16
  unsigned short* Gat   = Gbt + (size_t)D2_SZ * BT;           // [2048][2048] bf16
  unsigned short* Sbf   = Gat + (size_t)D2_SZ * BT;           // [2][16][128][128] bf16

  void* args[15] = {(void*)&feat, (void*)&Wq, (void*)&Wtb, (void*)&Wpb,
                    (void*)&Wta, (void*)&Wpa, (void*)&Wgb, (void*)&Wga,
                    (void*)&Nbf, (void*)&Wb, (void*)&Cproj, (void*)&Gbt,
                    (void*)&Gat, (void*)&Sbf, (void*)&out};
  hipLaunchCooperativeKernel((const void*)biute_mega, dim3(256), dim3(512),
                             args, 0, stream);
}

// Round 6
// 305.850 us; speedup vs baseline: 1.3646x; 1.3646x over previous
//
#include <hip/hip_runtime.h>
#include <hip/hip_bf16.h>
#include <math.h>

#define B_SZ 16
#define T_SZ 128
#define N_P 12
#define D_SZ 1024
#define D2_SZ 2048
#define BT 2048          // B*T tokens
#define KDIM 2048        // inner dim of projections (2D)
#define EPROJ 4096       // tb|pb|ta|pa row width

typedef __attribute__((ext_vector_type(8))) short short8;    // 8 bf16 = 4 VGPRs
typedef __attribute__((ext_vector_type(4))) float floatx4;   // MFMA C/D

__device__ inline void gload_lds16(const void* g, void* l) {
  __builtin_amdgcn_global_load_lds(
      (const __attribute__((address_space(1))) void*)g,
      (__attribute__((address_space(3))) void*)l, 16, 0, 0);
}

__device__ inline unsigned short f2bf(float x) {
  union { __hip_bfloat16 h; unsigned short u; } cv;
  cv.h = __float2bfloat16(x);
  return cv.u;
}
__device__ inline float bf2f(unsigned short u) {
  return __uint_as_float(((unsigned)u) << 16);
}

// ---------------------------------------------------------------------------
// Kernel A: build n = [g ; max] per token, bf16 out. One block per token.
// ---------------------------------------------------------------------------
__global__ __launch_bounds__(256) void build_n_kernel(
    const float* __restrict__ feat, const float* __restrict__ Wq,
    unsigned short* __restrict__ Nbf) {
  const int t = blockIdx.x;
  const int tid = threadIdx.x;
  const float4* fb4 = (const float4*)(feat + (size_t)t * N_P * D_SZ);
  const float4* wq4 = (const float4*)Wq;

  float4 q = {0.f, 0.f, 0.f, 0.f};
#pragma unroll
  for (int m = 0; m < N_P; ++m) {
    const float4 v = wq4[m * 256 + tid];
    q.x += v.x; q.y += v.y; q.z += v.z; q.w += v.w;
  }

  float4 fv[N_P];
  float part[N_P];
#pragma unroll
  for (int n = 0; n < N_P; ++n) {
    const float4 f = fb4[n * 256 + tid];
    fv[n] = f;
    part[n] = f.x * q.x + f.y * q.y + f.z * q.z + f.w * q.w;
  }

  __shared__ float wred[N_P * 4];
  const int lane = tid & 63;
  const int wave = tid >> 6;
#pragma unroll
  for (int n = 0; n < N_P; ++n) {
    float v = part[n];
#pragma unroll
    for (int off = 32; off; off >>= 1) v += __shfl_down(v, off);
    if (lane == 0) wred[n * 4 + wave] = v;
  }
  __syncthreads();

  float w[N_P];
#pragma unroll
  for (int n = 0; n < N_P; ++n)
    w[n] = wred[n * 4 + 0] + wred[n * 4 + 1] + wred[n * 4 + 2] + wred[n * 4 + 3];

  float4 g = {0.f, 0.f, 0.f, 0.f};
  float4 fm = {-INFINITY, -INFINITY, -INFINITY, -INFINITY};
#pragma unroll
  for (int n = 0; n < N_P; ++n) {
    const float4 f = fv[n];
    g.x += w[n] * f.x; g.y += w[n] * f.y; g.z += w[n] * f.z; g.w += w[n] * f.w;
    fm.x = fmaxf(fm.x, f.x); fm.y = fmaxf(fm.y, f.y);
    fm.z = fmaxf(fm.z, f.z); fm.w = fmaxf(fm.w, f.w);
  }
  ushort4 og, of;
  og.x = f2bf(g.x); og.y = f2bf(g.y); og.z = f2bf(g.z); og.w = f2bf(g.w);
  of.x = f2bf(fm.x); of.y = f2bf(fm.y); of.z = f2bf(fm.z); of.w = f2bf(fm.w);
  *(ushort4*)&Nbf[(size_t)t * D2_SZ + tid * 4] = og;
  *(ushort4*)&Nbf[(size_t)t * D2_SZ + D_SZ + tid * 4] = of;
}

// ---------------------------------------------------------------------------
// Kernel B: fused projection GEMM, bf16 MFMA, fp32 weights consumed DIRECTLY
// (no Wb roundtrip). 256x256 tile, BK=32, 8 waves (2Mx4N).
//  - A operand: ring-of-4 global_load_lds (verified round-1 path).
//  - B operand: reg-staged fp32 -> cvt bf16 -> ds_write_b128 into a 2-slot
//    parity buffer (T14 split; write lands one step before use).
// Ledger (steady state, per-step issue order = B(t+2):4 dwordx4, A(t+3):2
// gload_lds = 6 VMEM/step):
//   pre-wait outstanding at end of step t =
//     [A(t+1):2, B(t+1):4, A(t+2):2, B(t+2):4, A(t+3):2] = 14
//   vmcnt(8) waits exactly A(t+1) (ds_read next step) + B(t+1) regs
//     (BWRITE now); leaves [A(t+2), B(t+2), A(t+3)] = 8 in flight.
//   Tail: T=61 -> vmcnt(6), T=62 -> vmcnt(0), T=63 -> none.
// WAR: ASTAGE(t+3) hits ring slot (t-1)&3 whose ds_reads drained (lgkm0)
// before the end-of-(t-1) barrier; BWRITE(t+1) hits B parity (t+1)&1, last
// read at step t-1, drained likewise. Numerics identical to the cvt-kernel
// version (same RNE cvt, same accumulation order).
// ---------------------------------------------------------------------------
__global__ __launch_bounds__(512, 2) void gemm_fused(
    const unsigned short* __restrict__ X,
    const float* __restrict__ Wtb, const float* __restrict__ Wpb,
    const float* __restrict__ Wta, const float* __restrict__ Wpa,
    const float* __restrict__ Wgb, const float* __restrict__ Wga,
    unsigned short* __restrict__ Cproj,
    unsigned short* __restrict__ Gbt,
    unsigned short* __restrict__ Gat) {
  __shared__ __align__(16) unsigned short lds[6 * 8192];  // 96 KiB: A ring 4x16KB + B 2x16KB
  const int tid = threadIdx.x;
  const int lane = tid & 63;
  const int w = tid >> 6;           // 0..7
  const int quad = lane >> 4;
  const int l15 = lane & 15;
  const int wm = (w >> 2) * 128;    // wave row (2 waves in M)
  const int wn = (w & 3) * 64;      // wave col (4 waves in N)

  // XCD-aware bijective swizzle: 256 blocks, 8 XCDs.
  const int bid = blockIdx.x;
  const int swz = (bid & 7) * 32 + (bid >> 3);
  const int m0 = (swz & 7) * 256;   // token tile
  const int be = swz >> 3;          // 0..31 E-tile
  const int e0 = be * 256;

  // B source matrix (row-concatenated layout [tb|pb|ta|pa|gb|ga])
  const float* wsrc;
  int er;
  if (be < 4)       { wsrc = Wtb; er = e0; }
  else if (be < 8)  { wsrc = Wpb; er = e0 - 1024; }
  else if (be < 12) { wsrc = Wta; er = e0 - 2048; }
  else if (be < 16) { wsrc = Wpa; er = e0 - 3072; }
  else if (be < 24) { wsrc = Wgb; er = e0 - 4096; }
  else              { wsrc = Wga; er = e0 - 6144; }

  floatx4 acc[8][4];
#pragma unroll
  for (int mt = 0; mt < 8; ++mt)
#pragma unroll
    for (int nt = 0; nt < 4; ++nt) {
      floatx4 z = {0.f, 0.f, 0.f, 0.f};
      acc[mt][nt] = z;
    }

  // staging addresses: slot s covers (row = s>>2, swizzled chunk ccg)
  const unsigned short* srcA[2];
  int dstOffA[2];
  const float* srcB[2];
#pragma unroll
  for (int c = 0; c < 2; ++c) {
    const int s = tid + c * 512;              // 0..1023
    const int row = s >> 2;                   // 0..255
    const int ccg = (s & 3) ^ ((row >> 1) & 3);
    srcA[c] = X + (size_t)(m0 + row) * KDIM + ccg * 8;
    srcB[c] = wsrc + (size_t)(er + row) * KDIM + ccg * 8;
    dstOffA[c] = s * 8;
  }
  const int sB0 = tid * 8;            // B LDS ushort offsets within parity buf
  const int sB1 = tid * 8 + 4096;

  // loop-invariant swizzled fragment offsets (ushorts within a 16KB slot)
  int aofs[8], bofs[4];
#pragma unroll
  for (int mt = 0; mt < 8; ++mt) {
    const int row = wm + mt * 16 + l15;
    aofs[mt] = row * 32 + ((quad ^ ((row >> 1) & 3)) * 8);
  }
#pragma unroll
  for (int nt = 0; nt < 4; ++nt) {
    const int row = wn + nt * 16 + l15;
    bofs[nt] = row * 32 + ((quad ^ ((row >> 1) & 3)) * 8);
  }

#define ASTAGE(T)                                                             \
  {                                                                           \
    const int rb_ = ((T) & 3) * 8192;                                         \
    const int k0_ = (T) * 32;                                                 \
    gload_lds16(srcA[0] + k0_, &lds[rb_ + dstOffA[0]]);                       \
    gload_lds16(srcA[1] + k0_, &lds[rb_ + dstOffA[1]]);                       \
  }

#define BLOAD(T, Ra, Rb, Rc, Rd)                                              \
  {                                                                           \
    const int k0_ = (T) * 32;                                                 \
    Ra = *(const float4*)(srcB[0] + k0_);                                     \
    Rb = *(const float4*)(srcB[0] + k0_ + 4);                                 \
    Rc = *(const float4*)(srcB[1] + k0_);                                     \
    Rd = *(const float4*)(srcB[1] + k0_ + 4);                                 \
  }

#define BWRITE(T, Ra, Rb, Rc, Rd)                                             \
  {                                                                           \
    const int bb_ = 32768 + ((T) & 1) * 8192;                                 \
    short8 v0, v1;                                                            \
    v0[0] = (short)f2bf(Ra.x); v0[1] = (short)f2bf(Ra.y);                     \
    v0[2] = (short)f2bf(Ra.z); v0[3] = (short)f2bf(Ra.w);                     \
    v0[4] = (short)f2bf(Rb.x); v0[5] = (short)f2bf(Rb.y);                     \
    v0[6] = (short)f2bf(Rb.z); v0[7] = (short)f2bf(Rb.w);                     \
    v1[0] = (short)f2bf(Rc.x); v1[1] = (short)f2bf(Rc.y);                     \
    v1[2] = (short)f2bf(Rc.z); v1[3] = (short)f2bf(Rc.w);                     \
    v1[4] = (short)f2bf(Rd.x); v1[5] = (short)f2bf(Rd.y);                     \
    v1[6] = (short)f2bf(Rd.z); v1[7] = (short)f2bf(Rd.w);                     \
    *(short8*)&lds[bb_ + sB0] = v0;                                           \
    *(short8*)&lds[bb_ + sB1] = v1;                                           \
  }

  float4 r0a, r0b, r0c, r0d, r1a, r1b, r1c, r1d;

  // prologue: B(0)->set0, B(1)->set1, A(0..2); 14 loads in flight.
  BLOAD(0, r0a, r0b, r0c, r0d);
  BLOAD(1, r1a, r1b, r1c, r1d);
  ASTAGE(0); ASTAGE(1); ASTAGE(2);
  __builtin_amdgcn_sched_barrier(0);
  asm volatile("s_waitcnt vmcnt(4)" ::: "memory");  // B0,B1,A0 landed
  __builtin_amdgcn_sched_barrier(0);
  BWRITE(0, r0a, r0b, r0c, r0d);
  asm volatile("s_waitcnt lgkmcnt(0)" ::: "memory");
  __builtin_amdgcn_sched_barrier(0);
  __builtin_amdgcn_s_barrier();
  __builtin_amdgcn_sched_barrier(0);

#define STEP(T, La, Lb, Lc, Ld, Wa, Wb_, Wc, Wd)                              \
  {                                                                           \
    const int rb = ((T) & 3) * 8192;                                          \
    const int bb = 32768 + ((T) & 1) * 8192;                                  \
    short8 a[8], b[4];                                                        \
    _Pragma("unroll")                                                         \
    for (int mt = 0; mt < 8; ++mt)                                            \
      a[mt] = *(const short8*)&lds[rb + aofs[mt]];                            \
    _Pragma("unroll")                                                         \
    for (int nt = 0; nt < 4; ++nt)                                            \
      b[nt] = *(const short8*)&lds[bb + bofs[nt]];                            \
    if ((T) + 2 < 64) BLOAD((T) + 2, La, Lb, Lc, Ld);                         \
    if ((T) + 3 < 64) ASTAGE((T) + 3);                                        \
    __builtin_amdgcn_sched_barrier(0);                                        \
    __builtin_amdgcn_s_setprio(1);                                            \
    _Pragma("unroll")                                                         \
    for (int mt = 0; mt < 8; ++mt)                                            \
      _Pragma("unroll")                                                       \
      for (int nt = 0; nt < 4; ++nt)                                          \
        acc[mt][nt] = __builtin_amdgcn_mfma_f32_16x16x32_bf16(                \
            a[mt], b[nt], acc[mt][nt], 0, 0, 0);                              \
    __builtin_amdgcn_s_setprio(0);                                            \
    __builtin_amdgcn_sched_barrier(0);                                        \
    if ((T) <= 60) {                                                          \
      asm volatile("s_waitcnt vmcnt(8)" ::: "memory");                        \
    } else if ((T) == 61) {                                                   \
      asm volatile("s_waitcnt vmcnt(6)" ::: "memory");                        \
    } else if ((T) == 62) {                                                   \
      asm volatile("s_waitcnt vmcnt(0)" ::: "memory");                        \
    }                                                                         \
    __builtin_amdgcn_sched_barrier(0);                                        \
    if ((T) <= 62) BWRITE((T) + 1, Wa, Wb_, Wc, Wd);                          \
    if ((T) < 63) {                                                           \
      asm volatile("s_waitcnt lgkmcnt(0)" ::: "memory");                      \
      __builtin_amdgcn_sched_barrier(0);                                      \
      __builtin_amdgcn_s_barrier();                                           \
      __builtin_amdgcn_sched_barrier(0);                                      \
    }                                                                         \
  }

  for (int t = 0; t < 64; t += 2) {
    STEP(t,     r0a, r0b, r0c, r0d, r1a, r1b, r1c, r1d)
    STEP(t + 1, r1a, r1b, r1c, r1d, r0a, r0b, r0c, r0d)
  }
#undef STEP
#undef BWRITE
#undef BLOAD
#undef ASTAGE

  if (be < 16) {
#pragma unroll
    for (int mt = 0; mt < 8; ++mt)
#pragma unroll
      for (int nt = 0; nt < 4; ++nt) {
        const int col = e0 + wn + nt * 16 + l15;
#pragma unroll
        for (int r = 0; r < 4; ++r) {
          const int rowg = m0 + wm + mt * 16 + quad * 4 + r;
          Cproj[(size_t)rowg * EPROJ + col] = f2bf(acc[mt][nt][r]);
        }
      }
  } else {
    unsigned short* Gt = (be < 24) ? Gbt : Gat;
    const int fb = e0 - ((be < 24) ? 4096 : 6144);
#pragma unroll
    for (int mt = 0; mt < 8; ++mt)
#pragma unroll
      for (int nt = 0; nt < 4; ++nt) {
        const int f = fb + wn + nt * 16 + l15;
        const int tok0 = m0 + wm + mt * 16 + quad * 4;
        ushort4 o;
        o.x = f2bf(acc[mt][nt][0]); o.y = f2bf(acc[mt][nt][1]);
        o.z = f2bf(acc[mt][nt][2]); o.w = f2bf(acc[mt][nt][3]);
        *(ushort4*)&Gt[(size_t)f * BT + tok0] = o;
      }
  }
}

// ---------------------------------------------------------------------------
// Kernel 3: fused score. grid (16 batches, 2 branches, 2 j-chunks).
// Each block: 128(i) x 64(j) S-tile, full K=1024, epilogue mask+scale+bf16.
// ---------------------------------------------------------------------------
__global__ __launch_bounds__(256) void score_direct(
    const unsigned short* __restrict__ Cproj, unsigned short* __restrict__ Sbf) {
  const int b = blockIdx.x;
  const int br = blockIdx.y;
  const int jc = blockIdx.z;
  const int aoff = br ? 2048 : 0;   // ta : tb
  const int boff = aoff + 1024;     // pa : pb
  const int t0 = b * T_SZ;
  const int j0 = jc * 64;

  __shared__ __align__(16) unsigned short As[128 * 32];   // 8 KB
  __shared__ __align__(16) unsigned short Bs[64 * 32];    // 4 KB
  const int tid = threadIdx.x;
  const int lane = tid & 63;
  const int w = tid >> 6;
  const int wm = (w >> 1) * 64;    // i-offset (2 waves in M)
  const int wn = (w & 1) * 32;     // j-offset (2 waves in N)
  const int quad = lane >> 4;
  const int l15 = lane & 15;

  floatx4 acc[4][2];
#pragma unroll
  for (int mt = 0; mt < 4; ++mt)
#pragma unroll
    for (int nt = 0; nt < 2; ++nt) {
      floatx4 z = {0.f, 0.f, 0.f, 0.f};
      acc[mt][nt] = z;
    }

  const unsigned short* gA[2];
  unsigned short* lA[2];
#pragma unroll
  for (int c = 0; c < 2; ++c) {
    const int s = tid + c * 256;
    const int row = s >> 2;
    const int ccg = (s & 3) ^ ((row >> 1) & 3);
    gA[c] = Cproj + (size_t)(t0 + row) * EPROJ + aoff + ccg * 8;
    lA[c] = &As[(size_t)s * 8];
  }
  const unsigned short* gB;
  unsigned short* lB;
  {
    const int s = tid;
    const int row = s >> 2;
    const int ccg = (s & 3) ^ ((row >> 1) & 3);
    gB = Cproj + (size_t)(t0 + j0 + row) * EPROJ + boff + ccg * 8;
    lB = &Bs[(size_t)s * 8];
  }

  int aofs[4], bofs[2];
#pragma unroll
  for (int mt = 0; mt < 4; ++mt) {
    const int row = wm + mt * 16 + l15;
    aofs[mt] = row * 32 + ((quad ^ ((row >> 1) & 3)) * 8);
  }
#pragma unroll
  for (int nt = 0; nt < 2; ++nt) {
    const int row = wn + nt * 16 + l15;
    bofs[nt] = row * 32 + ((quad ^ ((row >> 1) & 3)) * 8);
  }

  for (int k0 = 0; k0 < D_SZ; k0 += 32) {   // K = 1024, 32 steps
    gload_lds16(gA[0] + k0, lA[0]);
    gload_lds16(gA[1] + k0, lA[1]);
    gload_lds16(gB + k0, lB);
    __syncthreads();
    short8 a[4], bb[2];
#pragma unroll
    for (int mt = 0; mt < 4; ++mt) a[mt] = *(const short8*)&As[aofs[mt]];
#pragma unroll
    for (int nt = 0; nt < 2; ++nt) bb[nt] = *(const short8*)&Bs[bofs[nt]];
#pragma unroll
    for (int mt = 0; mt < 4; ++mt)
#pragma unroll
      for (int nt = 0; nt < 2; ++nt)
        acc[mt][nt] = __builtin_amdgcn_mfma_f32_16x16x32_bf16(
            a[mt], bb[nt], acc[mt][nt], 0, 0, 0);
    __syncthreads();
  }

  const float scale = 0.022097086912079608f;  // 1/sqrt(2*1024)
  unsigned short* Sp = Sbf + ((size_t)(br * B_SZ + b)) * T_SZ * T_SZ;
#pragma unroll
  for (int mt = 0; mt < 4; ++mt)
#pragma unroll
    for (int nt = 0; nt < 2; ++nt) {
      const int j = j0 + wn + nt * 16 + l15;
#pragma unroll
      for (int r = 0; r < 4; ++r) {
        const int i = wm + mt * 16 + quad * 4 + r;
        const bool keep = br ? (j > i) : (j < i);
        Sp[(size_t)i * T_SZ + j] = f2bf(keep ? acc[mt][nt][r] * scale : 0.f);
      }
    }
}

// ---------------------------------------------------------------------------
// Kernel D: PV via MFMA, no LDS.
// ---------------------------------------------------------------------------
__global__ __launch_bounds__(256) void pv_mfma(
    const unsigned short* __restrict__ Nbf,
    const unsigned short* __restrict__ Sbf,
    const unsigned short* __restrict__ Gbt,
    const unsigned short* __restrict__ Gat,
    float* __restrict__ out) {
  const int ft = blockIdx.x;
  const int b = blockIdx.y;
  const int f0 = ft * 128;
  const int t0 = b * T_SZ;
  const int tid = threadIdx.x;
  const int lane = tid & 63;
  const int w = tid >> 6;
  const int wm = (w >> 1) * 64;   // token dim
  const int wn = (w & 1) * 64;    // f dim
  const int quad = lane >> 4;
  const int l15 = lane & 15;

  const unsigned short* Sb = Sbf + ((size_t)0 * B_SZ + b) * T_SZ * T_SZ;
  const unsigned short* Sa = Sbf + ((size_t)1 * B_SZ + b) * T_SZ * T_SZ;

  floatx4 acc[4][4];
#pragma unroll
  for (int mt = 0; mt < 4; ++mt)
#pragma unroll
    for (int nt = 0; nt < 4; ++nt) {
      floatx4 z = {0.f, 0.f, 0.f, 0.f};
      acc[mt][nt] = z;
    }

#pragma unroll
  for (int k0 = 0; k0 < T_SZ; k0 += 32) {
    short8 ab[4], aa[4], bb[4], ba[4];
#pragma unroll
    for (int mt = 0; mt < 4; ++mt) {
      const int i = wm + mt * 16 + l15;
      ab[mt] = *(const short8*)&Sb[(size_t)i * T_SZ + k0 + quad * 8];
      aa[mt] = *(const short8*)&Sa[(size_t)i * T_SZ + k0 + quad * 8];
    }
#pragma unroll
    for (int nt = 0; nt < 4; ++nt) {
      const int f = f0 + wn + nt * 16 + l15;
      bb[nt] = *(const short8*)&Gbt[(size_t)f * BT + t0 + k0 + quad * 8];
      ba[nt] = *(const short8*)&Gat[(size_t)f * BT + t0 + k0 + quad * 8];
    }
#pragma unroll
    for (int mt = 0; mt < 4; ++mt)
#pragma unroll
      for (int nt = 0; nt < 4; ++nt) {
        acc[mt][nt] = __builtin_amdgcn_mfma_f32_16x16x32_bf16(
            ab[mt], bb[nt], acc[mt][nt], 0, 0, 0);
        acc[mt][nt] = __builtin_amdgcn_mfma_f32_16x16x32_bf16(
            aa[mt], ba[nt], acc[mt][nt], 0, 0, 0);
      }
  }

#pragma unroll
  for (int mt = 0; mt < 4; ++mt)
#pragma unroll
    for (int nt = 0; nt < 4; ++nt) {
      const int f = f0 + wn + nt * 16 + l15;
#pragma unroll
      for (int r = 0; r < 4; ++r) {
        const int tok = t0 + wm + mt * 16 + quad * 4 + r;
        out[(size_t)tok * D2_SZ + f] =
            acc[mt][nt][r] + bf2f(Nbf[(size_t)tok * D2_SZ + f]);
      }
    }
}

// ---------------------------------------------------------------------------
extern "C" void kernel_launch(void* const* d_in, const int* in_sizes, int n_in,
                              void* d_out, int out_size, void* d_ws, size_t ws_size,
                              hipStream_t stream) {
  const float* feat = (const float*)d_in[0];
  const float* Wq  = (const float*)d_in[1];
  const float* Wtb = (const float*)d_in[2];
  const float* Wpb = (const float*)d_in[3];
  const float* Wgb = (const float*)d_in[4];  // dict order: gb before ta
  const float* Wta = (const float*)d_in[5];
  const float* Wpa = (const float*)d_in[6];
  const float* Wga = (const float*)d_in[7];
  float* out = (float*)d_out;

  unsigned short* ws = (unsigned short*)d_ws;
  unsigned short* Nbf   = ws;                                 // [2048][2048] bf16
  unsigned short* Cproj = Nbf + (size_t)BT * D2_SZ;           // [2048][4096] bf16
  unsigned short* Gbt   = Cproj + (size_t)BT * EPROJ;         // [2048][2048] bf16
  unsigned short* Gat   = Gbt + (size_t)D2_SZ * BT;           // [2048][2048] bf16
  unsigned short* Sbf   = Gat + (size_t)D2_SZ * BT;           // [2][16][128][128] bf16

  build_n_kernel<<<BT, 256, 0, stream>>>(feat, Wq, Nbf);
  gemm_fused<<<dim3(256), 512, 0, stream>>>(Nbf, Wtb, Wpb, Wta, Wpa, Wgb, Wga,
                                            Cproj, Gbt, Gat);
  score_direct<<<dim3(B_SZ, 2, 2), 256, 0, stream>>>(Cproj, Sbf);
  pv_mfma<<<dim3(D2_SZ / 128, B_SZ), 256, 0, stream>>>(Nbf, Sbf, Gbt, Gat, out);
}